// Round 1
// baseline (397.373 us; speedup 1.0000x reference)
//
#include <hip/hip_runtime.h>
#include <math.h>

// Problem constants (T5 encoder self-attention)
#define H_    16
#define S_    2048
#define DH_   64
#define DM_   1024
#define NTOK_ 4096          // B*S
#define NBIAS_ 4095         // 2*S-1 distinct relative positions

typedef __attribute__((ext_vector_type(8))) short short8;  // 8 bf16 (4 VGPRs)
typedef __attribute__((ext_vector_type(4))) float f32x4;   // MFMA C/D frag

#define MFMA16(a, b, c) __builtin_amdgcn_mfma_f32_16x16x32_bf16((a), (b), (c), 0, 0, 0)

__device__ __forceinline__ ushort f2bf(float f) {
  union { float f; unsigned u; } x; x.f = f;
  unsigned r = (x.u + 0x7FFFu + ((x.u >> 16) & 1u)) >> 16;  // RNE
  return (ushort)r;
}

// ---------------- fp32 -> bf16 cast (vectorized x4) ----------------
__global__ void cast_bf16_k(const float* __restrict__ in, ushort* __restrict__ out, int n) {
  int i = (blockIdx.x * blockDim.x + threadIdx.x) * 4;
  if (i >= n) return;
  const float4 v = *(const float4*)(in + i);
  ushort4 o;
  o.x = f2bf(v.x); o.y = f2bf(v.y); o.z = f2bf(v.z); o.w = f2bf(v.w);
  *(ushort4*)(out + i) = o;
}

// ---------------- T5 relative-position bias table ----------------
// biasTab[h][delta + 2047] = rel_emb[bucket(delta)][h], delta = key_pos - q_pos
__global__ void build_bias_k(const float* __restrict__ rel_emb, float* __restrict__ biasTab) {
  int d = blockIdx.x * blockDim.x + threadIdx.x;
  if (d >= NBIAS_) return;
  int rp = d - (S_ - 1);
  int ret = (rp > 0) ? 16 : 0;          // num_buckets//2 = 16 (bidirectional)
  int arp = rp < 0 ? -rp : rp;
  int bucket;
  if (arp < 8) {                         // max_exact = 8
    bucket = ret + arp;
  } else {
    float t = logf((float)arp * 0.125f); // log(arp/8), fp32 like jnp
    t = t / 2.772588722239781f;          // / log(16)
    t = t * 8.0f;                        // * (num_buckets - max_exact)
    int large = 8 + (int)t;              // trunc toward zero (positive -> floor)
    if (large > 15) large = 15;
    bucket = ret + large;
  }
  for (int h = 0; h < H_; ++h)
    biasTab[h * NBIAS_ + d] = rel_emb[bucket * H_ + h];
}

// ---------------- QKV projection: C = X @ W^T ----------------
// X: [4096][1024] bf16 row-major; W: [1024][1024] bf16 row-major (so B^T pattern).
// Tile: BM=128, BN=64, BK=32. 4 waves, each wave: 32 rows x 64 cols (2x4 MFMA tiles).
// z selects {Wq->Q, Wk->K, Wv->Vt}. Q/K stored [b][h][s][dh]; V stored transposed [b][h][dh][s].
__global__ __launch_bounds__(256) void gemm_qkv_k(
    const ushort* __restrict__ X,
    const ushort* __restrict__ Wq, const ushort* __restrict__ Wk, const ushort* __restrict__ Wv,
    ushort* __restrict__ Q, ushort* __restrict__ K, ushort* __restrict__ Vt)
{
  const int z = blockIdx.z;
  const ushort* __restrict__ W = (z == 0) ? Wq : (z == 1) ? Wk : Wv;
  __shared__ __align__(16) ushort As[128 * 32];  // 8 KB, row stride 64B -> 2-way (free)
  __shared__ __align__(16) ushort Ws[64 * 32];   // 4 KB

  const int tid = threadIdx.x;
  const int wave = tid >> 6, lane = tid & 63;
  const int l15 = lane & 15, l4 = lane >> 4;
  const int m0 = blockIdx.y * 128;
  const int n0 = blockIdx.x * 64;

  const int ar = tid >> 1, ac = (tid & 1) * 16;  // A stage: 16 elems/thread
  const int wr = tid >> 2, wc = (tid & 3) * 8;   // W stage: 8 elems/thread
  const ushort* gA = X + (size_t)(m0 + ar) * DM_ + ac;
  const ushort* gW = W + (size_t)(n0 + wr) * DM_ + wc;

  f32x4 acc[2][4];
#pragma unroll
  for (int mi = 0; mi < 2; ++mi)
#pragma unroll
    for (int ni = 0; ni < 4; ++ni) acc[mi][ni] = (f32x4){0.f, 0.f, 0.f, 0.f};

  for (int k0 = 0; k0 < DM_; k0 += 32) {
    short8 a0 = *(const short8*)(gA + k0);
    short8 a1 = *(const short8*)(gA + k0 + 8);
    short8 w0 = *(const short8*)(gW + k0);
    __syncthreads();
    *(short8*)&As[ar * 32 + ac]     = a0;
    *(short8*)&As[ar * 32 + ac + 8] = a1;
    *(short8*)&Ws[wr * 32 + wc]     = w0;
    __syncthreads();
    short8 af[2], bfr[4];
#pragma unroll
    for (int mi = 0; mi < 2; ++mi)
      af[mi] = *(const short8*)&As[(wave * 32 + mi * 16 + l15) * 32 + l4 * 8];
#pragma unroll
    for (int ni = 0; ni < 4; ++ni)
      bfr[ni] = *(const short8*)&Ws[(ni * 16 + l15) * 32 + l4 * 8];
#pragma unroll
    for (int mi = 0; mi < 2; ++mi)
#pragma unroll
      for (int ni = 0; ni < 4; ++ni)
        acc[mi][ni] = MFMA16(af[mi], bfr[ni], acc[mi][ni]);
  }

#pragma unroll
  for (int mi = 0; mi < 2; ++mi)
#pragma unroll
    for (int ni = 0; ni < 4; ++ni)
#pragma unroll
      for (int r = 0; r < 4; ++r) {
        int m = m0 + wave * 32 + mi * 16 + l4 * 4 + r;   // token
        int n = n0 + ni * 16 + l15;                      // d_model col
        int b = m >> 11, s = m & (S_ - 1);
        int h = n >> 6, d = n & 63;
        ushort bv = f2bf(acc[mi][ni][r]);
        if (z == 0)      Q [((size_t)(b * H_ + h) * S_ + s) * DH_ + d] = bv;
        else if (z == 1) K [((size_t)(b * H_ + h) * S_ + s) * DH_ + d] = bv;
        else             Vt[((size_t)(b * H_ + h) * DH_ + d) * S_ + s] = bv;
      }
}

// ---------------- Output projection: out = Ctx @ Wo^T (fp32 out) ----------------
__global__ __launch_bounds__(256) void gemm_out_k(
    const ushort* __restrict__ A, const ushort* __restrict__ W, float* __restrict__ out)
{
  __shared__ __align__(16) ushort As[128 * 32];
  __shared__ __align__(16) ushort Ws[64 * 32];
  const int tid = threadIdx.x;
  const int wave = tid >> 6, lane = tid & 63;
  const int l15 = lane & 15, l4 = lane >> 4;
  const int m0 = blockIdx.y * 128;
  const int n0 = blockIdx.x * 64;
  const int ar = tid >> 1, ac = (tid & 1) * 16;
  const int wr = tid >> 2, wc = (tid & 3) * 8;
  const ushort* gA = A + (size_t)(m0 + ar) * DM_ + ac;
  const ushort* gW = W + (size_t)(n0 + wr) * DM_ + wc;

  f32x4 acc[2][4];
#pragma unroll
  for (int mi = 0; mi < 2; ++mi)
#pragma unroll
    for (int ni = 0; ni < 4; ++ni) acc[mi][ni] = (f32x4){0.f, 0.f, 0.f, 0.f};

  for (int k0 = 0; k0 < DM_; k0 += 32) {
    short8 a0 = *(const short8*)(gA + k0);
    short8 a1 = *(const short8*)(gA + k0 + 8);
    short8 w0 = *(const short8*)(gW + k0);
    __syncthreads();
    *(short8*)&As[ar * 32 + ac]     = a0;
    *(short8*)&As[ar * 32 + ac + 8] = a1;
    *(short8*)&Ws[wr * 32 + wc]     = w0;
    __syncthreads();
    short8 af[2], bfr[4];
#pragma unroll
    for (int mi = 0; mi < 2; ++mi)
      af[mi] = *(const short8*)&As[(wave * 32 + mi * 16 + l15) * 32 + l4 * 8];
#pragma unroll
    for (int ni = 0; ni < 4; ++ni)
      bfr[ni] = *(const short8*)&Ws[(ni * 16 + l15) * 32 + l4 * 8];
#pragma unroll
    for (int mi = 0; mi < 2; ++mi)
#pragma unroll
      for (int ni = 0; ni < 4; ++ni)
        acc[mi][ni] = MFMA16(af[mi], bfr[ni], acc[mi][ni]);
  }

#pragma unroll
  for (int mi = 0; mi < 2; ++mi)
#pragma unroll
    for (int ni = 0; ni < 4; ++ni)
#pragma unroll
      for (int r = 0; r < 4; ++r) {
        int m = m0 + wave * 32 + mi * 16 + l4 * 4 + r;
        int n = n0 + ni * 16 + l15;
        out[(size_t)m * DM_ + n] = acc[mi][ni][r];
      }
}

// ---------------- Flash attention with T5 bias ----------------
// Grid: (S/64, B*H). Block: 256 thr = 4 waves; wave w owns q rows [qb + w*16, +16).
// Streams 64-key tiles: QK^T (MFMA, K direct from global) -> bias+online softmax
// -> P via LDS (C-layout -> A-layout transform) -> PV (MFMA, V^T direct from global).
__global__ __launch_bounds__(256) void attn_k(
    const ushort* __restrict__ Q, const ushort* __restrict__ K, const ushort* __restrict__ Vt,
    const float* __restrict__ biasTab, ushort* __restrict__ Ctx)
{
  __shared__ float bias_s[NBIAS_];                  // 16380 B: this head's bias row
  __shared__ __align__(16) ushort Ps[4][16 * 72];   // P per wave, stride 72 breaks conflicts

  const int tid = threadIdx.x;
  const int wave = tid >> 6, lane = tid & 63;
  const int l15 = lane & 15, l4 = lane >> 4;
  const int bh = blockIdx.y;            // b*H + h
  const int h = bh & (H_ - 1);
  const int b = bh >> 4;
  const int q0 = blockIdx.x * 64 + wave * 16;

  for (int i = tid; i < NBIAS_; i += 256) bias_s[i] = biasTab[h * NBIAS_ + i];
  __syncthreads();

  const ushort* Qh = Q  + (size_t)bh * S_ * DH_;
  const ushort* Kh = K  + (size_t)bh * S_ * DH_;
  const ushort* Vh = Vt + (size_t)bh * DH_ * S_;

  short8 qf[2];
#pragma unroll
  for (int kk = 0; kk < 2; ++kk)
    qf[kk] = *(const short8*)(Qh + (size_t)(q0 + l15) * DH_ + kk * 32 + l4 * 8);

  f32x4 of[4];
#pragma unroll
  for (int nt = 0; nt < 4; ++nt) of[nt] = (f32x4){0.f, 0.f, 0.f, 0.f};
  float mrow[4] = {-1e30f, -1e30f, -1e30f, -1e30f};
  float lrow[4] = {0.f, 0.f, 0.f, 0.f};

  ushort* Pw = &Ps[wave][0];

  for (int kt = 0; kt < S_; kt += 64) {
    // ---- QK^T: 16 q-rows x 64 keys ----
    f32x4 sc[4];
#pragma unroll
    for (int nt = 0; nt < 4; ++nt) sc[nt] = (f32x4){0.f, 0.f, 0.f, 0.f};
#pragma unroll
    for (int kk = 0; kk < 2; ++kk) {
#pragma unroll
      for (int nt = 0; nt < 4; ++nt) {
        short8 kf = *(const short8*)(Kh + (size_t)(kt + nt * 16 + l15) * DH_ + kk * 32 + l4 * 8);
        sc[nt] = MFMA16(qf[kk], kf, sc[nt]);
      }
    }
    // ---- scale + bias (C-layout: row = l4*4+r, col = kt + nt*16 + l15) ----
    float s[4][4];
#pragma unroll
    for (int nt = 0; nt < 4; ++nt)
#pragma unroll
      for (int r = 0; r < 4; ++r)
        s[nt][r] = sc[nt][r] * 0.125f +
                   bias_s[(kt + nt * 16 + l15) - (q0 + l4 * 4 + r) + (S_ - 1)];
    // ---- online softmax (row reductions across 16-lane col groups) ----
    float alpha[4];
#pragma unroll
    for (int r = 0; r < 4; ++r) {
      float mx = s[0][r];
#pragma unroll
      for (int nt = 1; nt < 4; ++nt) mx = fmaxf(mx, s[nt][r]);
#pragma unroll
      for (int off = 1; off < 16; off <<= 1) mx = fmaxf(mx, __shfl_xor(mx, off, 64));
      float mnew = fmaxf(mrow[r], mx);
      float ps = 0.f;
#pragma unroll
      for (int nt = 0; nt < 4; ++nt) {
        float p = __expf(s[nt][r] - mnew);
        ps += p;
        Pw[(l4 * 4 + r) * 72 + nt * 16 + l15] = f2bf(p);
      }
#pragma unroll
      for (int off = 1; off < 16; off <<= 1) ps += __shfl_xor(ps, off, 64);
      alpha[r] = __expf(mrow[r] - mnew);
      lrow[r] = lrow[r] * alpha[r] + ps;
      mrow[r] = mnew;
    }
#pragma unroll
    for (int nt = 0; nt < 4; ++nt)
#pragma unroll
      for (int r = 0; r < 4; ++r) of[nt][r] *= alpha[r];
    // ---- PV: P (A-layout via LDS) @ V (B-frag from V^T, contiguous) ----
#pragma unroll
    for (int kk = 0; kk < 2; ++kk) {
      short8 pf = *(const short8*)&Pw[l15 * 72 + kk * 32 + l4 * 8];
#pragma unroll
      for (int nt = 0; nt < 4; ++nt) {
        short8 vf = *(const short8*)(Vh + (size_t)(nt * 16 + l15) * S_ + kt + kk * 32 + l4 * 8);
        of[nt] = MFMA16(pf, vf, of[nt]);
      }
    }
  }

  // ---- finalize: ctx[token][h*64 + dh] ----
#pragma unroll
  for (int nt = 0; nt < 4; ++nt)
#pragma unroll
    for (int r = 0; r < 4; ++r) {
      int t = b * S_ + q0 + l4 * 4 + r;
      float v = of[nt][r] / lrow[r];
      Ctx[(size_t)t * DM_ + h * 64 + nt * 16 + l15] = f2bf(v);
    }
}

// ---------------- launch ----------------
extern "C" void kernel_launch(void* const* d_in, const int* in_sizes, int n_in,
                              void* d_out, int out_size, void* d_ws, size_t ws_size,
                              hipStream_t stream) {
  const float* hs  = (const float*)d_in[0];
  const float* Wq  = (const float*)d_in[1];
  const float* Wk  = (const float*)d_in[2];
  const float* Wv  = (const float*)d_in[3];
  const float* Wo  = (const float*)d_in[4];
  const float* rel = (const float*)d_in[5];
  float* out = (float*)d_out;

  // Workspace carve-up (bf16 buffers as ushort). Ctx aliases Xb (X dead after QKV GEMM).
  ushort* Xb  = (ushort*)d_ws;                         // 4096x1024
  ushort* Wqb = Xb  + (size_t)NTOK_ * DM_;             // 1024x1024 each
  ushort* Wkb = Wqb + (size_t)DM_ * DM_;
  ushort* Wvb = Wkb + (size_t)DM_ * DM_;
  ushort* Wob = Wvb + (size_t)DM_ * DM_;
  ushort* Qd  = Wob + (size_t)DM_ * DM_;               // [b][h][s][dh]
  ushort* Kd  = Qd  + (size_t)NTOK_ * DM_;
  ushort* Vtd = Kd  + (size_t)NTOK_ * DM_;             // [b][h][dh][s]
  float* biasTab = (float*)(Vtd + (size_t)NTOK_ * DM_); // [H][4095]
  ushort* Ctx = Xb;                                     // alias: safe, stream-ordered

  cast_bf16_k<<<4096, 256, 0, stream>>>(hs, Xb, NTOK_ * DM_);
  cast_bf16_k<<<1024, 256, 0, stream>>>(Wq, Wqb, DM_ * DM_);
  cast_bf16_k<<<1024, 256, 0, stream>>>(Wk, Wkb, DM_ * DM_);
  cast_bf16_k<<<1024, 256, 0, stream>>>(Wv, Wvb, DM_ * DM_);
  cast_bf16_k<<<1024, 256, 0, stream>>>(Wo, Wob, DM_ * DM_);
  build_bias_k<<<16, 256, 0, stream>>>(rel, biasTab);

  gemm_qkv_k<<<dim3(16, 32, 3), 256, 0, stream>>>(Xb, Wqb, Wkb, Wvb, Qd, Kd, Vtd);
  attn_k<<<dim3(S_ / 64, 2 * H_), 256, 0, stream>>>(Qd, Kd, Vtd, biasTab, Ctx);
  gemm_out_k<<<dim3(16, 32), 256, 0, stream>>>(Ctx, Wob, out);
}